// Round 1
// baseline (706.465 us; speedup 1.0000x reference)
//
#include <hip/hip_runtime.h>

// VQ-VAE eval forward, MI355X.
// inputs:  d_in[0] = inputs  fp32 [64,64,32,32] NCHW  (4,194,304)
//          d_in[1] = emb     fp32 [1024,64]           (65,536)
// outputs in d_out (fp32, concatenated flat):
//          [0]                  loss
//          [1 .. 4194304]       quantized NCHW
//          [4194305]            perplexity
//          [4194306 .. end]     encodings one-hot [65536,1024]
//
// ws layout (floats): [0..1023] se[k]; [1024..2047] hist(int); [2048] lossacc;
//                     [2304 ..] idx[65536] (int)   -> ~272 KB total

#define NROWS 65536
#define DIM   64
#define KCB   1024

__global__ __launch_bounds__(256) void vq_init_kernel(
    const float* __restrict__ emb, float* __restrict__ se,
    int* __restrict__ hist, float* __restrict__ lossacc)
{
    const int k = blockIdx.x * 256 + threadIdx.x;   // 0..1023
    const float4* e4p = (const float4*)(emb + (k << 6));
    float s = 0.f;
#pragma unroll
    for (int q = 0; q < 16; ++q) {
        float4 e4 = e4p[q];
        s = fmaf(e4.x, e4.x, s); s = fmaf(e4.y, e4.y, s);
        s = fmaf(e4.z, e4.z, s); s = fmaf(e4.w, e4.w, s);
    }
    se[k] = s;
    hist[k] = 0;
    if (k == 0) lossacc[0] = 0.f;
}

// One thread per row. x[64] in VGPRs; e rows via uniform (scalarizable) loads.
// Interleaves the 256 MB encodings zero-fill (1 MB per block) into the k-loop.
__global__ __launch_bounds__(256) void vq_argmin_kernel(
    const float* __restrict__ inp, const float* __restrict__ emb,
    const float* __restrict__ se, float* __restrict__ lossacc,
    int* __restrict__ hist, int* __restrict__ idxout,
    float2* __restrict__ encz)
{
    const int tid = threadIdx.x;
    const int row = blockIdx.x * 256 + tid;
    const int n  = row >> 10;
    const int hw = row & 1023;
    const float* xb = inp + n * (DIM * 1024) + hw;  // NCHW: stride 1024 per channel

    float x[DIM];
#pragma unroll
    for (int d = 0; d < DIM; ++d) x[d] = xb[d << 10];   // coalesced across lanes

    float sx = 0.f;
#pragma unroll
    for (int d = 0; d < DIM; ++d) sx = fmaf(x[d], x[d], sx);

    // encodings zero-fill: this block owns a contiguous 1 MB = 131072 float2
    float2* ezp = encz + (size_t)blockIdx.x * 131072 + tid;
    const float2 z2 = make_float2(0.f, 0.f);

    float min1 = 3.0e38f, min2 = 3.0e38f;
    int   i1 = 0, i2 = 0;

    for (int k = 0; k < KCB; ++k) {
        const float4* e4p = (const float4*)(emb + (k << 6));
        float a0 = 0.f, a1 = 0.f, a2 = 0.f, a3 = 0.f;
#pragma unroll
        for (int q = 0; q < 16; ++q) {
            float4 e4 = e4p[q];
            a0 = fmaf(x[4*q+0], e4.x, a0);
            a1 = fmaf(x[4*q+1], e4.y, a1);
            a2 = fmaf(x[4*q+2], e4.z, a2);
            a3 = fmaf(x[4*q+3], e4.w, a3);
        }
        float dk = se[k] - 2.f * ((a0 + a1) + (a2 + a3));  // ||x||^2 omitted (common)
        if ((k & 1) == 0) ezp[(size_t)(k >> 1) << 8] = z2; // fire-and-forget zero store
        if (dk < min1)      { min2 = min1; i2 = i1; min1 = dk; i1 = k; }
        else if (dk < min2) { min2 = dk; i2 = k; }
    }

    // fp64 fix-up for near-ties (fp32 error ~1e-7 << 3e-5 threshold << typical gap 2e-3)
    if (min2 - min1 < 3e-5f) {
        const float* e1 = emb + (i1 << 6);
        const float* e2 = emb + (i2 << 6);
        double d1 = 0.0, d2 = 0.0;
#pragma unroll
        for (int d = 0; d < DIM; ++d) {
            double t1 = (double)x[d] - (double)e1[d];
            double t2 = (double)x[d] - (double)e2[d];
            d1 = fma(t1, t1, d1);
            d2 = fma(t2, t2, d2);
        }
        if (d2 < d1 || (d2 == d1 && i2 < i1)) { i1 = i2; min1 = min2; }
    }

    idxout[row] = i1;
    atomicAdd(&hist[i1], 1);

    // loss partial: sum over rows of ||x - e_i1||^2 = sx + min1
    float lv = sx + min1;
    __shared__ float red[256];
    red[tid] = lv;
    __syncthreads();
    for (int s = 128; s > 0; s >>= 1) {
        if (tid < s) red[tid] += red[tid + s];
        __syncthreads();
    }
    if (tid == 0) atomicAdd(lossacc, red[0]);
}

// quantized (NCHW) gather + one-hot ones scatter
__global__ __launch_bounds__(256) void vq_out_kernel(
    const float* __restrict__ emb, const int* __restrict__ idx,
    float* __restrict__ outq, float* __restrict__ enc)
{
    const int o  = blockIdx.x * 256 + threadIdx.x;
    const int n  = o >> 16;          // / (64*1024)
    const int c  = (o >> 10) & 63;
    const int hw = o & 1023;
    const int row = (n << 10) | hw;
    const int k = idx[row];
    outq[o] = emb[(k << 6) | c];     // STE output == gathered code value
    if (c == 0) enc[((size_t)row << 10) | (size_t)k] = 1.0f;
}

__global__ __launch_bounds__(256) void vq_final_kernel(
    const int* __restrict__ hist, const float* __restrict__ lossacc,
    float* __restrict__ out)
{
    const int tid = threadIdx.x;
    float s = 0.f;
    for (int k = tid; k < KCB; k += 256) {
        float p = (float)hist[k] * (1.f / 65536.f);
        s += p * logf(p + 1e-10f);
    }
    __shared__ float red[256];
    red[tid] = s;
    __syncthreads();
    for (int st = 128; st > 0; st >>= 1) {
        if (tid < st) red[tid] += red[tid + st];
        __syncthreads();
    }
    if (tid == 0) {
        out[0] = 0.25f * lossacc[0] * (1.f / 4194304.f);
        out[4194305] = expf(-red[0]);
    }
}

extern "C" void kernel_launch(void* const* d_in, const int* in_sizes, int n_in,
                              void* d_out, int out_size, void* d_ws, size_t ws_size,
                              hipStream_t stream) {
    const float* inp = (const float*)d_in[0];
    const float* emb = (const float*)d_in[1];
    float* out = (float*)d_out;

    float* wsf     = (float*)d_ws;
    float* se      = wsf;                    // 1024 floats
    int*   hist    = (int*)(wsf + 1024);     // 1024 ints
    float* lossacc = wsf + 2048;             // 1 float
    int*   idx     = (int*)(wsf + 2304);     // 65536 ints

    float* outq = out + 1;
    float* enc  = out + 4194306;

    vq_init_kernel<<<4, 256, 0, stream>>>(emb, se, hist, lossacc);
    vq_argmin_kernel<<<256, 256, 0, stream>>>(inp, emb, se, lossacc, hist, idx,
                                              (float2*)enc);
    vq_out_kernel<<<16384, 256, 0, stream>>>(emb, idx, outq, enc);
    vq_final_kernel<<<1, 256, 0, stream>>>(hist, lossacc, out);
}

// Round 2
// 577.377 us; speedup vs baseline: 1.2236x; 1.2236x over previous
//
#include <hip/hip_runtime.h>

// VQ-VAE eval forward, MI355X.
// inputs:  d_in[0] = inputs  fp32 [64,64,32,32] NCHW  (4,194,304)
//          d_in[1] = emb     fp32 [1024,64]           (65,536)
// outputs in d_out (fp32, concatenated flat):
//          [0]                  loss
//          [1 .. 4194304]       quantized NCHW
//          [4194305]            perplexity
//          [4194306 .. end]     encodings one-hot [65536,1024]  (256 MB)
//
// Structure (R2): K-split x8 for occupancy. 2048 blocks: (rowblk 0..255) x
// (chunk 0..7 of 128 codes). Chunk staged in LDS (32 KB), x[64] in VGPRs
// (launch_bounds caps 128 VGPR -> 4 waves/SIMD). Per-chunk top-2 partials
// (16 B/row/chunk = 8 MB) are parked in the first 8 MB of the encodings
// region; combine kernel merges, does fp64 near-tie fixup, loss/hist, and
// zeroes its own partial slots. The remaining 248 MB zero-fill is
// interleaved into the compute loop (overlaps VALU work with HBM writes).

#define NROWS 65536
#define DIM   64
#define KCB   1024
#define CHUNK 128
#define KSPLIT 8

__global__ __launch_bounds__(256) void vq_init_kernel(
    const float* __restrict__ emb, float* __restrict__ se,
    int* __restrict__ hist, float* __restrict__ lossacc)
{
    const int k = blockIdx.x * 256 + threadIdx.x;   // 0..1023
    const float4* e4p = (const float4*)(emb + (k << 6));
    float s = 0.f;
#pragma unroll
    for (int q = 0; q < 16; ++q) {
        float4 e4 = e4p[q];
        s = fmaf(e4.x, e4.x, s); s = fmaf(e4.y, e4.y, s);
        s = fmaf(e4.z, e4.z, s); s = fmaf(e4.w, e4.w, s);
    }
    se[k] = s;
    hist[k] = 0;
    if (k == 0) lossacc[0] = 0.f;
}

// blockIdx.x in [0,2048): chunk = b&7, rowblk = b>>3.
__global__ __launch_bounds__(256, 4) void vq_partial_kernel(
    const float* __restrict__ inp, const float* __restrict__ emb,
    const float* __restrict__ se, float4* __restrict__ part,
    float2* __restrict__ encz2)
{
    __shared__ float lds[CHUNK * DIM];     // 32 KB
    __shared__ float se_lds[CHUNK];

    const int tid   = threadIdx.x;
    const int chunk = blockIdx.x & 7;
    const int row   = (blockIdx.x >> 3) * 256 + tid;
    const int n  = row >> 10;
    const int hw = row & 1023;
    const float* xb = inp + n * (DIM * 1024) + hw;  // NCHW: stride 1024/channel

    // x into VGPRs (coalesced across lanes: consecutive hw)
    float x[DIM];
#pragma unroll
    for (int d = 0; d < DIM; ++d) x[d] = xb[d << 10];

    // stage chunk codes into LDS: 2048 float4, 8 per thread, coalesced
    {
        const float4* src = (const float4*)(emb + chunk * (CHUNK * DIM));
        float4* dst = (float4*)lds;
#pragma unroll
        for (int i = 0; i < 8; ++i) dst[tid + i * 256] = src[tid + i * 256];
        if (tid < CHUNK) se_lds[tid] = se[chunk * CHUNK + tid];
    }
    __syncthreads();

    // zero-fill: this block owns 15872 contiguous float2 of [8MB..256MB) enc
    float2* ezp = encz2 + (size_t)blockIdx.x * 15872 + tid;
    const float2 z2 = make_float2(0.f, 0.f);

    float min1 = 3.0e38f, min2 = 3.0e38f;
    int   i1 = 0, i2 = 0;

#pragma unroll 2
    for (int c = 0; c < CHUNK; ++c) {
        const float4* e4p = (const float4*)&lds[c << 6];
        float a0 = 0.f, a1 = 0.f, a2 = 0.f, a3 = 0.f;
#pragma unroll
        for (int q = 0; q < 16; ++q) {
            float4 e4 = e4p[q];          // broadcast ds_read_b128
            a0 = fmaf(x[4*q+0], e4.x, a0);
            a1 = fmaf(x[4*q+1], e4.y, a1);
            a2 = fmaf(x[4*q+2], e4.z, a2);
            a3 = fmaf(x[4*q+3], e4.w, a3);
        }
        float dk = se_lds[c] - 2.f * ((a0 + a1) + (a2 + a3));  // ||x||^2 dropped
        if (c < 124 && (c & 1) == 0)
            ezp[(size_t)(c >> 1) * 256] = z2;                  // fire-and-forget
        int k = chunk * CHUNK + c;
        if (dk < min1)      { min2 = min1; i2 = i1; min1 = dk; i1 = k; }
        else if (dk < min2) { min2 = dk; i2 = k; }
    }

    part[((size_t)row << 3) | chunk] =
        make_float4(min1, __int_as_float(i1), min2, __int_as_float(i2));
}

__global__ __launch_bounds__(256) void vq_combine_kernel(
    const float* __restrict__ inp, const float* __restrict__ emb,
    float4* __restrict__ part, float* __restrict__ lossacc,
    int* __restrict__ hist, int* __restrict__ idxout)
{
    const int tid = threadIdx.x;
    const int row = blockIdx.x * 256 + tid;
    const int n  = row >> 10;
    const int hw = row & 1023;
    const float* xb = inp + n * (DIM * 1024) + hw;

    float x[DIM];
#pragma unroll
    for (int d = 0; d < DIM; ++d) x[d] = xb[d << 10];
    float sx = 0.f;
#pragma unroll
    for (int d = 0; d < DIM; ++d) sx = fmaf(x[d], x[d], sx);

    float m1 = 3.0e38f, m2 = 3.0e38f;
    int   i1 = 0, i2 = 0;
#pragma unroll
    for (int c = 0; c < KSPLIT; ++c) {
        float4 v = part[((size_t)row << 3) | c];
        float a = v.x; int ia = __float_as_int(v.y);
        float b = v.z; int ib = __float_as_int(v.w);
        if (a < m1) {
            if (m1 < b) { m2 = m1; i2 = i1; } else { m2 = b; i2 = ib; }
            m1 = a; i1 = ia;
        } else if (a < m2) { m2 = a; i2 = ia; }
    }

    // zero own partial slots (this thread is the only reader)
    const float4 z4 = make_float4(0.f, 0.f, 0.f, 0.f);
#pragma unroll
    for (int c = 0; c < KSPLIT; ++c) part[((size_t)row << 3) | c] = z4;

    // fp64 fix-up for near-ties (fp32 err ~1e-7 << 3e-5 << typical gap ~2e-3)
    if (m2 - m1 < 3e-5f) {
        const float* e1 = emb + (i1 << 6);
        const float* e2 = emb + (i2 << 6);
        double d1 = 0.0, d2 = 0.0;
#pragma unroll
        for (int d = 0; d < DIM; ++d) {
            double t1 = (double)x[d] - (double)e1[d];
            double t2 = (double)x[d] - (double)e2[d];
            d1 = fma(t1, t1, d1);
            d2 = fma(t2, t2, d2);
        }
        if (d2 < d1 || (d2 == d1 && i2 < i1)) { i1 = i2; m1 = m2; }
    }

    idxout[row] = i1;
    atomicAdd(&hist[i1], 1);

    float lv = sx + m1;       // ||x - e_i1||^2
    __shared__ float red[256];
    red[tid] = lv;
    __syncthreads();
    for (int s = 128; s > 0; s >>= 1) {
        if (tid < s) red[tid] += red[tid + s];
        __syncthreads();
    }
    if (tid == 0) atomicAdd(lossacc, red[0]);
}

// quantized (NCHW) gather + one-hot ones scatter
__global__ __launch_bounds__(256) void vq_out_kernel(
    const float* __restrict__ emb, const int* __restrict__ idx,
    float* __restrict__ outq, float* __restrict__ enc)
{
    const int o  = blockIdx.x * 256 + threadIdx.x;
    const int n  = o >> 16;          // / (64*1024)
    const int c  = (o >> 10) & 63;
    const int hw = o & 1023;
    const int row = (n << 10) | hw;
    const int k = idx[row];
    outq[o] = emb[(k << 6) | c];     // STE output == gathered code value
    if (c == 0) enc[((size_t)row << 10) | (size_t)k] = 1.0f;
}

__global__ __launch_bounds__(256) void vq_final_kernel(
    const int* __restrict__ hist, const float* __restrict__ lossacc,
    float* __restrict__ out)
{
    const int tid = threadIdx.x;
    float s = 0.f;
    for (int k = tid; k < KCB; k += 256) {
        float p = (float)hist[k] * (1.f / 65536.f);
        s += p * logf(p + 1e-10f);
    }
    __shared__ float red[256];
    red[tid] = s;
    __syncthreads();
    for (int st = 128; st > 0; st >>= 1) {
        if (tid < st) red[tid] += red[tid + st];
        __syncthreads();
    }
    if (tid == 0) {
        out[0] = 0.25f * lossacc[0] * (1.f / 4194304.f);
        out[4194305] = expf(-red[0]);
    }
}

extern "C" void kernel_launch(void* const* d_in, const int* in_sizes, int n_in,
                              void* d_out, int out_size, void* d_ws, size_t ws_size,
                              hipStream_t stream) {
    const float* inp = (const float*)d_in[0];
    const float* emb = (const float*)d_in[1];
    float* out = (float*)d_out;

    float* wsf     = (float*)d_ws;
    float* se      = wsf;                    // 1024 floats
    int*   hist    = (int*)(wsf + 1024);     // 1024 ints
    float* lossacc = wsf + 2048;             // 1 float
    int*   idx     = (int*)(wsf + 2304);     // 65536 ints

    float* outq = out + 1;
    float* enc  = out + 4194306;             // 67,108,864 floats
    float4* part = (float4*)enc;             // first 8 MB: per-chunk partials
    float2* encz2 = (float2*)(enc + 2097152); // remaining 248 MB zero-fill

    vq_init_kernel<<<4, 256, 0, stream>>>(emb, se, hist, lossacc);
    vq_partial_kernel<<<2048, 256, 0, stream>>>(inp, emb, se, part, encz2);
    vq_combine_kernel<<<256, 256, 0, stream>>>(inp, emb, part, lossacc, hist, idx);
    vq_out_kernel<<<16384, 256, 0, stream>>>(emb, idx, outq, enc);
    vq_final_kernel<<<1, 256, 0, stream>>>(hist, lossacc, out);
}

// Round 3
// 526.227 us; speedup vs baseline: 1.3425x; 1.0972x over previous
//
#include <hip/hip_runtime.h>

// VQ-VAE eval forward, MI355X — R3: bf16-split MFMA argmin.
// inputs:  d_in[0] = inputs  fp32 [64,64,32,32] NCHW  (4,194,304)
//          d_in[1] = emb     fp32 [1024,64]           (65,536)
// outputs in d_out (fp32, flat): loss | quantized NCHW (4194304) |
//          perplexity | encodings [65536,1024] (256 MB)
//
// Distance argmin via S = X·E^T with bf16 hi/lo split (3 MFMA terms,
// ~1e-6 abs err vs ~2e-5 code gaps). Staging arrays (A-frag x, B-frag e)
// are parked in the encodings region of d_out (dead until vq_encfill
// rewrites it). ws keeps only se/hist/loss/sumx2/idx (~272 KB).

#define NROWS 65536
#define DIM   64
#define KCB   1024

typedef __attribute__((ext_vector_type(8))) short  short8;
typedef __attribute__((ext_vector_type(4))) float  floatx4;

__device__ inline unsigned short f2bf(float f) {
    unsigned u = __float_as_uint(f);
    u = u + 0x7fffu + ((u >> 16) & 1u);      // round-to-nearest-even
    return (unsigned short)(u >> 16);
}
__device__ inline float bf2f(unsigned short h) {
    return __uint_as_float(((unsigned)h) << 16);
}

// ---- init: se[k], hist=0, scalars=0, e -> B-fragment-ordered bf16 hi/lo ----
// B-frag layout (16x16x32): elem (ct,kt,lane,j) = emb[code=ct*16+(lane&15)]
//                           [dim=kt*32+(lane>>4)*8+j]
__global__ __launch_bounds__(256) void vq_init_kernel(
    const float* __restrict__ emb, float* __restrict__ se,
    int* __restrict__ hist, float* __restrict__ lossacc, float* __restrict__ sumx2,
    short8* __restrict__ ebh, short8* __restrict__ ebl)
{
    const int code = blockIdx.x * 256 + threadIdx.x;   // 0..1023
    const float* e = emb + (code << 6);
    float s = 0.f;
    float v[DIM];
#pragma unroll
    for (int d = 0; d < DIM; ++d) { v[d] = e[d]; s = fmaf(v[d], v[d], s); }
    se[code] = s;
    hist[code] = 0;
    if (code == 0) { lossacc[0] = 0.f; sumx2[0] = 0.f; }

    const int ct = code >> 4;
#pragma unroll
    for (int jg = 0; jg < 8; ++jg) {                   // dims jg*8 .. jg*8+7
        const int kt   = jg >> 2;
        const int lane = (code & 15) + 16 * (jg & 3);
        short8 h8, l8;
#pragma unroll
        for (int j = 0; j < 8; ++j) {
            float x = v[jg * 8 + j];
            unsigned short h = f2bf(x);
            h8[j] = (short)h;
            l8[j] = (short)f2bf(x - bf2f(h));
        }
        ebh[(ct * 2 + kt) * 64 + lane] = h8;
        ebl[(ct * 2 + kt) * 64 + lane] = l8;
    }
}

// ---- xprep: NCHW fp32 -> A-fragment-ordered bf16 hi/lo, + sum(x^2) ----
// A-frag layout: elem (s16,kt,lane,j) = x[row=s16*16+(lane&15)]
//                [dim=kt*32+(lane>>4)*8+j]
__global__ __launch_bounds__(256) void vq_xprep_kernel(
    const float* __restrict__ inp, short8* __restrict__ xah,
    short8* __restrict__ xal, float* __restrict__ sumx2)
{
    const int tid = threadIdx.x;
    const int r   = tid & 31;
    const int jg  = tid >> 5;                 // 0..7 -> dims jg*8..+8
    const int row = blockIdx.x * 32 + r;
    const int n   = row >> 10;
    const int hw  = row & 1023;
    const float* base = inp + n * (DIM * 1024) + hw;

    float v[8];
    float s2 = 0.f;
#pragma unroll
    for (int j = 0; j < 8; ++j) {
        v[j] = base[(jg * 8 + j) << 10];      // coalesced across r
        s2 = fmaf(v[j], v[j], s2);
    }

    short8 h8, l8;
#pragma unroll
    for (int j = 0; j < 8; ++j) {
        unsigned short h = f2bf(v[j]);
        h8[j] = (short)h;
        l8[j] = (short)f2bf(v[j] - bf2f(h));
    }
    const int s16  = row >> 4;
    const int kt   = jg >> 2;
    const int lane = (row & 15) + 16 * (jg & 3);
    xah[(s16 * 2 + kt) * 64 + lane] = h8;
    xal[(s16 * 2 + kt) * 64 + lane] = l8;

    __shared__ float red[256];
    red[tid] = s2;
    __syncthreads();
    for (int st = 128; st > 0; st >>= 1) {
        if (tid < st) red[tid] += red[tid + st];
        __syncthreads();
    }
    if (tid == 0) atomicAdd(sumx2, red[0]);
}

// ---- MFMA argmin: wave = 32 rows (2 subtiles) x all 1024 codes ----
__global__ __launch_bounds__(256) void vq_mfma_argmin(
    const short8* __restrict__ xah, const short8* __restrict__ xal,
    const short8* __restrict__ ebh, const short8* __restrict__ ebl,
    const float* __restrict__ se, int* __restrict__ idxout,
    float* __restrict__ lossacc)
{
    const int tid  = threadIdx.x;
    const int lane = tid & 63;
    const int wid  = tid >> 6;
    const int rbase = (blockIdx.x * 4 + wid) * 32;
    const int s16   = rbase >> 4;

    short8 ah[2][2], al[2][2];
#pragma unroll
    for (int s = 0; s < 2; ++s)
#pragma unroll
        for (int kt = 0; kt < 2; ++kt) {
            ah[s][kt] = xah[((s16 + s) * 2 + kt) * 64 + lane];
            al[s][kt] = xal[((s16 + s) * 2 + kt) * 64 + lane];
        }

    float minv[2][4]; int mini[2][4];
#pragma unroll
    for (int s = 0; s < 2; ++s)
#pragma unroll
        for (int r = 0; r < 4; ++r) { minv[s][r] = 3.0e38f; mini[s][r] = 0; }

    const int cl = lane & 15;
    short8 b0h = ebh[lane], b0l = ebl[lane];
    short8 b1h = ebh[64 + lane], b1l = ebl[64 + lane];

    for (int ct = 0; ct < 64; ++ct) {
        short8 ch0 = b0h, cB0 = b0l, ch1 = b1h, cB1 = b1l;
        if (ct < 63) {                         // double-buffer next B-frags
            b0h = ebh[(ct + 1) * 128 + lane];
            b0l = ebl[(ct + 1) * 128 + lane];
            b1h = ebh[(ct + 1) * 128 + 64 + lane];
            b1l = ebl[(ct + 1) * 128 + 64 + lane];
        }
        floatx4 a0 = {0.f, 0.f, 0.f, 0.f};
        floatx4 a1 = {0.f, 0.f, 0.f, 0.f};
        // S = xh*eh + xh*el + xl*eh, fp32 accumulate
        a0 = __builtin_amdgcn_mfma_f32_16x16x32_bf16(ah[0][0], ch0, a0, 0, 0, 0);
        a0 = __builtin_amdgcn_mfma_f32_16x16x32_bf16(ah[0][1], ch1, a0, 0, 0, 0);
        a0 = __builtin_amdgcn_mfma_f32_16x16x32_bf16(ah[0][0], cB0, a0, 0, 0, 0);
        a0 = __builtin_amdgcn_mfma_f32_16x16x32_bf16(ah[0][1], cB1, a0, 0, 0, 0);
        a0 = __builtin_amdgcn_mfma_f32_16x16x32_bf16(al[0][0], ch0, a0, 0, 0, 0);
        a0 = __builtin_amdgcn_mfma_f32_16x16x32_bf16(al[0][1], ch1, a0, 0, 0, 0);
        a1 = __builtin_amdgcn_mfma_f32_16x16x32_bf16(ah[1][0], ch0, a1, 0, 0, 0);
        a1 = __builtin_amdgcn_mfma_f32_16x16x32_bf16(ah[1][1], ch1, a1, 0, 0, 0);
        a1 = __builtin_amdgcn_mfma_f32_16x16x32_bf16(ah[1][0], cB0, a1, 0, 0, 0);
        a1 = __builtin_amdgcn_mfma_f32_16x16x32_bf16(ah[1][1], cB1, a1, 0, 0, 0);
        a1 = __builtin_amdgcn_mfma_f32_16x16x32_bf16(al[1][0], ch0, a1, 0, 0, 0);
        a1 = __builtin_amdgcn_mfma_f32_16x16x32_bf16(al[1][1], ch1, a1, 0, 0, 0);

        const float sel = se[ct * 16 + cl];
        const int  code = ct * 16 + cl;
#pragma unroll
        for (int r = 0; r < 4; ++r) {
            float d0 = fmaf(-2.f, a0[r], sel);
            if (d0 < minv[0][r]) { minv[0][r] = d0; mini[0][r] = code; }
            float d1 = fmaf(-2.f, a1[r], sel);
            if (d1 < minv[1][r]) { minv[1][r] = d1; mini[1][r] = code; }
        }
    }

    // reduce (val,idx) across the 16 lanes of each quad-group; C/D layout:
    // col=lane&15 (code slice), row = (lane>>4)*4 + r
    float lossp = 0.f;
#pragma unroll
    for (int s = 0; s < 2; ++s)
#pragma unroll
        for (int r = 0; r < 4; ++r) {
            float v = minv[s][r]; int i = mini[s][r];
#pragma unroll
            for (int m = 1; m <= 8; m <<= 1) {
                float ov = __shfl_xor(v, m, 64);
                int   oi = __shfl_xor(i, m, 64);
                if (ov < v || (ov == v && oi < i)) { v = ov; i = oi; }
            }
            if ((lane & 15) == 0) {
                int row = rbase + s * 16 + (lane >> 4) * 4 + r;
                idxout[row] = i;
                lossp += v;                     // d'_min for this row
            }
        }
#pragma unroll
    for (int m = 1; m <= 32; m <<= 1) lossp += __shfl_xor(lossp, m, 64);
    if (lane == 0) atomicAdd(lossacc, lossp);
}

// ---- encodings: full-row streamed writes (zeros + one 1.0) + hist ----
__global__ __launch_bounds__(256) void vq_encfill_kernel(
    const int* __restrict__ idx, int* __restrict__ hist,
    float2* __restrict__ enc2)
{
    const int tid = threadIdx.x;
    const int row = blockIdx.x * 4 + (tid >> 6);
    const int l   = tid & 63;
    const int k   = idx[row];
    if (l == 0) atomicAdd(&hist[k], 1);
    float2* p = enc2 + (size_t)row * 512 + l * 8;
#pragma unroll
    for (int i = 0; i < 8; ++i) {
        float2 v = make_float2(0.f, 0.f);
        if ((k >> 1) == l * 8 + i) ((float*)&v)[k & 1] = 1.0f;
        p[i] = v;
    }
}

// ---- quantized NCHW gather (exact fp32 codes) ----
__global__ __launch_bounds__(256) void vq_qout_kernel(
    const float* __restrict__ emb, const int* __restrict__ idx,
    float* __restrict__ outq)
{
    const int o  = blockIdx.x * 256 + threadIdx.x;
    const int n  = o >> 16;
    const int c  = (o >> 10) & 63;
    const int hw = o & 1023;
    const int k  = idx[(n << 10) | hw];
    outq[o] = emb[(k << 6) | c];
}

__global__ __launch_bounds__(256) void vq_final_kernel(
    const int* __restrict__ hist, const float* __restrict__ lossacc,
    const float* __restrict__ sumx2, float* __restrict__ out)
{
    const int tid = threadIdx.x;
    float s = 0.f;
    for (int k = tid; k < KCB; k += 256) {
        float p = (float)hist[k] * (1.f / 65536.f);
        s += p * logf(p + 1e-10f);
    }
    __shared__ float red[256];
    red[tid] = s;
    __syncthreads();
    for (int st = 128; st > 0; st >>= 1) {
        if (tid < st) red[tid] += red[tid + st];
        __syncthreads();
    }
    if (tid == 0) {
        // mean||x-q||^2 = (sum x^2 + sum d'_min) / numel
        out[0] = 0.25f * (sumx2[0] + lossacc[0]) * (1.f / 4194304.f);
        out[4194305] = expf(-red[0]);
    }
}

extern "C" void kernel_launch(void* const* d_in, const int* in_sizes, int n_in,
                              void* d_out, int out_size, void* d_ws, size_t ws_size,
                              hipStream_t stream) {
    const float* inp = (const float*)d_in[0];
    const float* emb = (const float*)d_in[1];
    float* out = (float*)d_out;

    float* wsf     = (float*)d_ws;
    float* se      = wsf;                     // 1024 f
    int*   hist    = (int*)(wsf + 1024);      // 1024 i
    float* lossacc = wsf + 2048;              // sum d'_min
    float* sumx2   = wsf + 2049;              // sum x^2
    int*   idx     = (int*)(wsf + 2304);      // 65536 i

    float* outq = out + 1;
    float* enc  = out + 4194306;              // 67,108,864 f (256 MB)

    // staging arrays parked inside enc region (dead until vq_encfill):
    // out+4194308 is 16 B aligned (byte 16,777,232).
    short8* xah = (short8*)(out + 4194308);              // 8 MB
    short8* xal = (short8*)(out + 4194308 + 2097152);    // 8 MB
    short8* ebh = (short8*)(out + 4194308 + 4194304);    // 128 KB
    short8* ebl = (short8*)(out + 4194308 + 4194304 + 32768);

    vq_init_kernel <<<4,     256, 0, stream>>>(emb, se, hist, lossacc, sumx2, ebh, ebl);
    vq_xprep_kernel<<<2048,  256, 0, stream>>>(inp, xah, xal, sumx2);
    vq_mfma_argmin <<<512,   256, 0, stream>>>(xah, xal, ebh, ebl, se, idx, lossacc);
    vq_encfill_kernel<<<16384, 256, 0, stream>>>(idx, hist, (float2*)enc);
    vq_qout_kernel <<<16384, 256, 0, stream>>>(emb, idx, outq);
    vq_final_kernel<<<1,     256, 0, stream>>>(hist, lossacc, sumx2, out);
}

// Round 5
// 403.404 us; speedup vs baseline: 1.7513x; 1.3045x over previous
//
#include <hip/hip_runtime.h>

// VQ-VAE eval forward, MI355X — R5: R4 with clang-native float2 for
// __builtin_nontemporal_store (HIP_vector_type float2 rejected by builtin).
// inputs:  d_in[0] = inputs  fp32 [64,64,32,32] NCHW  (4,194,304)
//          d_in[1] = emb     fp32 [1024,64]           (65,536)
// outputs in d_out (fp32, flat): loss | quantized NCHW (4194304) |
//          perplexity | encodings [65536,1024] (256 MB)
//
// Distance argmin via S = X·E^T with bf16 hi/lo split (3 MFMA terms,
// ~1e-6 abs err vs ~2e-5 code gaps). Staging arrays (A-frag x, B-frag e)
// are parked in the encodings region of d_out (dead until vq_encfill
// rewrites it). ws keeps only se/hist/loss/sumx2/idx (~272 KB).

#define NROWS 65536
#define DIM   64
#define KCB   1024

typedef __attribute__((ext_vector_type(8))) short  short8;
typedef __attribute__((ext_vector_type(4))) float  floatx4;
typedef __attribute__((ext_vector_type(2))) float  floatx2;

__device__ inline unsigned short f2bf(float f) {
    unsigned u = __float_as_uint(f);
    u = u + 0x7fffu + ((u >> 16) & 1u);      // round-to-nearest-even
    return (unsigned short)(u >> 16);
}
__device__ inline float bf2f(unsigned short h) {
    return __uint_as_float(((unsigned)h) << 16);
}

// ---- init: se[k], hist=0, scalars=0, e -> B-fragment-ordered bf16 hi/lo ----
// B-frag layout (16x16x32): elem (ct,kt,lane,j) = emb[code=ct*16+(lane&15)]
//                           [dim=kt*32+(lane>>4)*8+j]
__global__ __launch_bounds__(256) void vq_init_kernel(
    const float* __restrict__ emb, float* __restrict__ se,
    int* __restrict__ hist, float* __restrict__ lossacc, float* __restrict__ sumx2,
    short8* __restrict__ ebh, short8* __restrict__ ebl)
{
    const int code = blockIdx.x * 256 + threadIdx.x;   // 0..1023
    const float* e = emb + (code << 6);
    float s = 0.f;
    float v[DIM];
#pragma unroll
    for (int d = 0; d < DIM; ++d) { v[d] = e[d]; s = fmaf(v[d], v[d], s); }
    se[code] = s;
    hist[code] = 0;
    if (code == 0) { lossacc[0] = 0.f; sumx2[0] = 0.f; }

    const int ct = code >> 4;
#pragma unroll
    for (int jg = 0; jg < 8; ++jg) {                   // dims jg*8 .. jg*8+7
        const int kt   = jg >> 2;
        const int lane = (code & 15) + 16 * (jg & 3);
        short8 h8, l8;
#pragma unroll
        for (int j = 0; j < 8; ++j) {
            float x = v[jg * 8 + j];
            unsigned short h = f2bf(x);
            h8[j] = (short)h;
            l8[j] = (short)f2bf(x - bf2f(h));
        }
        ebh[(ct * 2 + kt) * 64 + lane] = h8;
        ebl[(ct * 2 + kt) * 64 + lane] = l8;
    }
}

// ---- xprep: NCHW fp32 -> A-fragment-ordered bf16 hi/lo, + sum(x^2) ----
__global__ __launch_bounds__(256) void vq_xprep_kernel(
    const float* __restrict__ inp, short8* __restrict__ xah,
    short8* __restrict__ xal, float* __restrict__ sumx2)
{
    const int tid = threadIdx.x;
    const int r   = tid & 31;
    const int jg  = tid >> 5;                 // 0..7 -> dims jg*8..+8
    const int row = blockIdx.x * 32 + r;
    const int n   = row >> 10;
    const int hw  = row & 1023;
    const float* base = inp + n * (DIM * 1024) + hw;

    float v[8];
    float s2 = 0.f;
#pragma unroll
    for (int j = 0; j < 8; ++j) {
        v[j] = base[(jg * 8 + j) << 10];      // coalesced across r
        s2 = fmaf(v[j], v[j], s2);
    }

    short8 h8, l8;
#pragma unroll
    for (int j = 0; j < 8; ++j) {
        unsigned short h = f2bf(v[j]);
        h8[j] = (short)h;
        l8[j] = (short)f2bf(v[j] - bf2f(h));
    }
    const int s16  = row >> 4;
    const int kt   = jg >> 2;
    const int lane = (row & 15) + 16 * (jg & 3);
    xah[(s16 * 2 + kt) * 64 + lane] = h8;
    xal[(s16 * 2 + kt) * 64 + lane] = l8;

    __shared__ float red[256];
    red[tid] = s2;
    __syncthreads();
    for (int st = 128; st > 0; st >>= 1) {
        if (tid < st) red[tid] += red[tid + st];
        __syncthreads();
    }
    if (tid == 0) atomicAdd(sumx2, red[0]);
}

// ---- MFMA argmin: wave = 32 rows (2 subtiles) x all 1024 codes ----
__global__ __launch_bounds__(256) void vq_mfma_argmin(
    const short8* __restrict__ xah, const short8* __restrict__ xal,
    const short8* __restrict__ ebh, const short8* __restrict__ ebl,
    const float* __restrict__ se, int* __restrict__ idxout,
    float* __restrict__ lossacc)
{
    const int tid  = threadIdx.x;
    const int lane = tid & 63;
    const int wid  = tid >> 6;
    const int rbase = (blockIdx.x * 4 + wid) * 32;
    const int s16   = rbase >> 4;

    short8 ah[2][2], al[2][2];
#pragma unroll
    for (int s = 0; s < 2; ++s)
#pragma unroll
        for (int kt = 0; kt < 2; ++kt) {
            ah[s][kt] = xah[((s16 + s) * 2 + kt) * 64 + lane];
            al[s][kt] = xal[((s16 + s) * 2 + kt) * 64 + lane];
        }

    float minv[2][4]; int mini[2][4];
#pragma unroll
    for (int s = 0; s < 2; ++s)
#pragma unroll
        for (int r = 0; r < 4; ++r) { minv[s][r] = 3.0e38f; mini[s][r] = 0; }

    const int cl = lane & 15;
    short8 b0h = ebh[lane], b0l = ebl[lane];
    short8 b1h = ebh[64 + lane], b1l = ebl[64 + lane];

    for (int ct = 0; ct < 64; ++ct) {
        short8 ch0 = b0h, cB0 = b0l, ch1 = b1h, cB1 = b1l;
        if (ct < 63) {                         // double-buffer next B-frags
            b0h = ebh[(ct + 1) * 128 + lane];
            b0l = ebl[(ct + 1) * 128 + lane];
            b1h = ebh[(ct + 1) * 128 + 64 + lane];
            b1l = ebl[(ct + 1) * 128 + 64 + lane];
        }
        floatx4 a0 = {0.f, 0.f, 0.f, 0.f};
        floatx4 a1 = {0.f, 0.f, 0.f, 0.f};
        // S = xh*eh + xh*el + xl*eh, fp32 accumulate
        a0 = __builtin_amdgcn_mfma_f32_16x16x32_bf16(ah[0][0], ch0, a0, 0, 0, 0);
        a0 = __builtin_amdgcn_mfma_f32_16x16x32_bf16(ah[0][1], ch1, a0, 0, 0, 0);
        a0 = __builtin_amdgcn_mfma_f32_16x16x32_bf16(ah[0][0], cB0, a0, 0, 0, 0);
        a0 = __builtin_amdgcn_mfma_f32_16x16x32_bf16(ah[0][1], cB1, a0, 0, 0, 0);
        a0 = __builtin_amdgcn_mfma_f32_16x16x32_bf16(al[0][0], ch0, a0, 0, 0, 0);
        a0 = __builtin_amdgcn_mfma_f32_16x16x32_bf16(al[0][1], ch1, a0, 0, 0, 0);
        a1 = __builtin_amdgcn_mfma_f32_16x16x32_bf16(ah[1][0], ch0, a1, 0, 0, 0);
        a1 = __builtin_amdgcn_mfma_f32_16x16x32_bf16(ah[1][1], ch1, a1, 0, 0, 0);
        a1 = __builtin_amdgcn_mfma_f32_16x16x32_bf16(ah[1][0], cB0, a1, 0, 0, 0);
        a1 = __builtin_amdgcn_mfma_f32_16x16x32_bf16(ah[1][1], cB1, a1, 0, 0, 0);
        a1 = __builtin_amdgcn_mfma_f32_16x16x32_bf16(al[1][0], ch0, a1, 0, 0, 0);
        a1 = __builtin_amdgcn_mfma_f32_16x16x32_bf16(al[1][1], ch1, a1, 0, 0, 0);

        const float sel = se[ct * 16 + cl];
        const int  code = ct * 16 + cl;
#pragma unroll
        for (int r = 0; r < 4; ++r) {
            float d0 = fmaf(-2.f, a0[r], sel);
            if (d0 < minv[0][r]) { minv[0][r] = d0; mini[0][r] = code; }
            float d1 = fmaf(-2.f, a1[r], sel);
            if (d1 < minv[1][r]) { minv[1][r] = d1; mini[1][r] = code; }
        }
    }

    // reduce (val,idx) across the 16 lanes of each quad-group; C/D layout:
    // col=lane&15 (code slice), row = (lane>>4)*4 + r
    float lossp = 0.f;
#pragma unroll
    for (int s = 0; s < 2; ++s)
#pragma unroll
        for (int r = 0; r < 4; ++r) {
            float v = minv[s][r]; int i = mini[s][r];
#pragma unroll
            for (int m = 1; m <= 8; m <<= 1) {
                float ov = __shfl_xor(v, m, 64);
                int   oi = __shfl_xor(i, m, 64);
                if (ov < v || (ov == v && oi < i)) { v = ov; i = oi; }
            }
            if ((lane & 15) == 0) {
                int row = rbase + s * 16 + (lane >> 4) * 4 + r;
                idxout[row] = i;
                lossp += v;                     // d'_min for this row
            }
        }
#pragma unroll
    for (int m = 1; m <= 32; m <<= 1) lossp += __shfl_xor(lossp, m, 64);
    if (lane == 0) atomicAdd(lossacc, lossp);
}

// ---- encodings: wave-per-row, lane-contiguous nontemporal floatx2 stores ----
__global__ __launch_bounds__(256) void vq_encfill_kernel(
    const int* __restrict__ idx, int* __restrict__ hist,
    floatx2* __restrict__ enc2)
{
    const int tid  = threadIdx.x;
    const int row  = (blockIdx.x << 2) + (tid >> 6);
    const int lane = tid & 63;
    const int k    = idx[row];
    if (lane == 0) atomicAdd(&hist[k], 1);
    floatx2* p = enc2 + ((size_t)row << 9) + lane;    // row*512 floatx2
    const int tf2 = k >> 1, tc = k & 1;
#pragma unroll
    for (int i = 0; i < 8; ++i) {                     // f2 index lane + 64*i
        floatx2 v = {0.f, 0.f};
        if (tf2 == lane + (i << 6)) v[tc] = 1.0f;
        __builtin_nontemporal_store(v, &p[(size_t)i << 6]);
    }
}

// ---- quantized NCHW gather, LDS-tiled for coalesced writes ----
// block = (n, 64-hw slab): stage 64 code rows in LDS (pad 65), write
// outq[n][c][hw] with lanes varying hw -> 256 B coalesced stores.
__global__ __launch_bounds__(256) void vq_qout_kernel(
    const float4* __restrict__ emb4, const int* __restrict__ idx,
    float* __restrict__ outq)
{
    __shared__ float q[64 * 65];
    __shared__ int ks[64];
    const int tid = threadIdx.x;
    const int n   = blockIdx.x >> 4;
    const int hw0 = (blockIdx.x & 15) << 6;
    if (tid < 64) ks[tid] = idx[(n << 10) + hw0 + tid];
    __syncthreads();
#pragma unroll
    for (int i = 0; i < 4; ++i) {
        int flat = tid + (i << 8);        // 0..1023 = 64 rows x 16 float4
        int hw = flat >> 4;
        int f4 = flat & 15;
        float4 v = emb4[(ks[hw] << 4) + f4];   // coalesced 256 B row reads, L2-hot
        float* dst = &q[hw * 65 + (f4 << 2)];
        dst[0] = v.x; dst[1] = v.y; dst[2] = v.z; dst[3] = v.w;
    }
    __syncthreads();
    const int lane_hw = tid & 63;
    const int cw = tid >> 6;              // wave id 0..3 -> c block
    float* ob = outq + ((size_t)n << 16) + hw0 + lane_hw;
#pragma unroll
    for (int j = 0; j < 16; ++j) {
        int c = cw * 16 + j;
        __builtin_nontemporal_store(q[lane_hw * 65 + c], &ob[(size_t)c << 10]);
    }
}

__global__ __launch_bounds__(256) void vq_final_kernel(
    const int* __restrict__ hist, const float* __restrict__ lossacc,
    const float* __restrict__ sumx2, float* __restrict__ out)
{
    const int tid = threadIdx.x;
    float s = 0.f;
    for (int k = tid; k < KCB; k += 256) {
        float p = (float)hist[k] * (1.f / 65536.f);
        s += p * logf(p + 1e-10f);
    }
    __shared__ float red[256];
    red[tid] = s;
    __syncthreads();
    for (int st = 128; st > 0; st >>= 1) {
        if (tid < st) red[tid] += red[tid + st];
        __syncthreads();
    }
    if (tid == 0) {
        // mean||x-q||^2 = (sum x^2 + sum d'_min) / numel
        out[0] = 0.25f * (sumx2[0] + lossacc[0]) * (1.f / 4194304.f);
        out[4194305] = expf(-red[0]);
    }
}

extern "C" void kernel_launch(void* const* d_in, const int* in_sizes, int n_in,
                              void* d_out, int out_size, void* d_ws, size_t ws_size,
                              hipStream_t stream) {
    const float* inp = (const float*)d_in[0];
    const float* emb = (const float*)d_in[1];
    float* out = (float*)d_out;

    float* wsf     = (float*)d_ws;
    float* se      = wsf;                     // 1024 f
    int*   hist    = (int*)(wsf + 1024);      // 1024 i
    float* lossacc = wsf + 2048;              // sum d'_min
    float* sumx2   = wsf + 2049;              // sum x^2
    int*   idx     = (int*)(wsf + 2304);      // 65536 i

    float* outq = out + 1;
    float* enc  = out + 4194306;              // 67,108,864 f (256 MB)

    // staging arrays parked inside enc region (dead until vq_encfill):
    // out+4194308 is 16 B aligned (byte 16,777,232).
    short8* xah = (short8*)(out + 4194308);              // 8 MB
    short8* xal = (short8*)(out + 4194308 + 2097152);    // 8 MB
    short8* ebh = (short8*)(out + 4194308 + 4194304);    // 128 KB
    short8* ebl = (short8*)(out + 4194308 + 4194304 + 32768);

    vq_init_kernel <<<4,     256, 0, stream>>>(emb, se, hist, lossacc, sumx2, ebh, ebl);
    vq_xprep_kernel<<<2048,  256, 0, stream>>>(inp, xah, xal, sumx2);
    vq_mfma_argmin <<<512,   256, 0, stream>>>(xah, xal, ebh, ebl, se, idx, lossacc);
    vq_encfill_kernel<<<16384, 256, 0, stream>>>(idx, hist, (floatx2*)enc);
    vq_qout_kernel <<<1024,  256, 0, stream>>>((const float4*)emb, idx, outq);
    vq_final_kernel<<<1,     256, 0, stream>>>(hist, lossacc, sumx2, out);
}

// Round 7
// 380.345 us; speedup vs baseline: 1.8574x; 1.0606x over previous
//
#include <hip/hip_runtime.h>

// VQ-VAE eval forward, MI355X — R7: R6 mega-fusion with the ebh/ebl aliasing
// bug fixed (each B-frag array is 128 KB = 32768 floats; R6 spaced them only
// 64 KB apart in ws -> init-kernel race corrupted distances). B-frags now
// parked in the quantized region of d_out (dead until vq_qout, which runs
// after the mega kernel; enc region is streamed concurrently so it cannot
// host them).
// inputs:  d_in[0] = inputs  fp32 [64,64,32,32] NCHW  (4,194,304)
//          d_in[1] = emb     fp32 [1024,64]           (65,536)
// outputs in d_out (fp32, flat): loss | quantized NCHW (4194304) |
//          perplexity | encodings [65536,1024] (256 MB)

#define NROWS 65536
#define DIM   64
#define KCB   1024

typedef __attribute__((ext_vector_type(8))) short  short8;
typedef __attribute__((ext_vector_type(4))) float  floatx4;
typedef __attribute__((ext_vector_type(2))) float  floatx2;

__device__ inline unsigned short f2bf(float f) {
    unsigned u = __float_as_uint(f);
    u = u + 0x7fffu + ((u >> 16) & 1u);      // round-to-nearest-even
    return (unsigned short)(u >> 16);
}
__device__ inline float bf2f(unsigned short h) {
    return __uint_as_float(((unsigned)h) << 16);
}

// ---- init: se[k], hist=0, scalars=0, e -> B-fragment-ordered bf16 hi/lo ----
// B-frag layout (16x16x32): elem (ct,kt,lane,j) = emb[code=ct*16+(lane&15)]
//                           [dim=kt*32+(lane>>4)*8+j]
__global__ __launch_bounds__(256) void vq_init_kernel(
    const float* __restrict__ emb, float* __restrict__ se,
    int* __restrict__ hist, float* __restrict__ lossacc, float* __restrict__ sumx2,
    short8* __restrict__ ebh, short8* __restrict__ ebl)
{
    const int code = blockIdx.x * 256 + threadIdx.x;   // 0..1023
    const float* e = emb + (code << 6);
    float s = 0.f;
    float v[DIM];
#pragma unroll
    for (int d = 0; d < DIM; ++d) { v[d] = e[d]; s = fmaf(v[d], v[d], s); }
    se[code] = s;
    hist[code] = 0;
    if (code == 0) { lossacc[0] = 0.f; sumx2[0] = 0.f; }

    const int ct = code >> 4;
#pragma unroll
    for (int jg = 0; jg < 8; ++jg) {                   // dims jg*8 .. jg*8+7
        const int kt   = jg >> 2;
        const int lane = (code & 15) + 16 * (jg & 3);
        short8 h8, l8;
#pragma unroll
        for (int j = 0; j < 8; ++j) {
            float x = v[jg * 8 + j];
            unsigned short h = f2bf(x);
            h8[j] = (short)h;
            l8[j] = (short)f2bf(x - bf2f(h));
        }
        ebh[(ct * 2 + kt) * 64 + lane] = h8;
        ebl[(ct * 2 + kt) * 64 + lane] = l8;
    }
}

// ---- mega: block = 128 rows. Phase A: x load + bf16-split -> LDS A-frags.
//      Phase B: MFMA argmin over all 1024 codes (B-frags double-buffered from
//      global). Phase C: idx/hist/loss. Phase D: per-wave enc-row streaming.
__global__ __launch_bounds__(256) void vq_mega_kernel(
    const float* __restrict__ inp, const short8* __restrict__ ebh,
    const short8* __restrict__ ebl, const float* __restrict__ se,
    int* __restrict__ idxout, int* __restrict__ hist,
    float* __restrict__ lossacc, float* __restrict__ sumx2,
    floatx2* __restrict__ enc2)
{
    __shared__ short8 fragH[1024];   // [s16_loc(8)][kt(2)][lane(64)], 16 KB
    __shared__ short8 fragL[1024];   // 16 KB
    __shared__ int ks[128];

    const int tid  = threadIdx.x;
    const int rblk = blockIdx.x << 7;        // first row of this block
    const int n    = rblk >> 10;             // 128 | 1024 -> single n per block
    const int hw0  = rblk & 1023;

    // ---- Phase A ----
    {
        const int r_loc = tid & 127;
        const int half  = tid >> 7;          // dims half*32 .. +31
        const float* base = inp + n * 65536 + hw0 + r_loc;
        float v[32];
        float s2 = 0.f;
#pragma unroll
        for (int j = 0; j < 32; ++j) {
            v[j] = base[(half * 32 + j) << 10];   // 256 B coalesced per instr
            s2 = fmaf(v[j], v[j], s2);
        }
        const int s16 = r_loc >> 4;
#pragma unroll
        for (int jg2 = 0; jg2 < 4; ++jg2) {       // jg = half*4 + jg2
            short8 h8, l8;
#pragma unroll
            for (int jj = 0; jj < 8; ++jj) {
                float x = v[jg2 * 8 + jj];
                unsigned short h = f2bf(x);
                h8[jj] = (short)h;
                l8[jj] = (short)f2bf(x - bf2f(h));
            }
            // kt = jg>>2 = half; lane = (row&15) + 16*(jg&3), jg&3 = jg2
            int fi = (s16 * 2 + half) * 64 + (r_loc & 15) + (jg2 << 4);
            fragH[fi] = h8;
            fragL[fi] = l8;
        }
#pragma unroll
        for (int m = 1; m <= 32; m <<= 1) s2 += __shfl_xor(s2, m, 64);
        if ((tid & 63) == 0) atomicAdd(sumx2, s2);
    }
    __syncthreads();

    // ---- Phase B: MFMA argmin (identical numerics to R5) ----
    const int lane = tid & 63;
    const int wid  = tid >> 6;

    short8 ah[2][2], al[2][2];
#pragma unroll
    for (int s = 0; s < 2; ++s)
#pragma unroll
        for (int kt = 0; kt < 2; ++kt) {
            int fi = ((wid * 2 + s) * 2 + kt) * 64 + lane;
            ah[s][kt] = fragH[fi];
            al[s][kt] = fragL[fi];
        }

    float minv[2][4]; int mini[2][4];
#pragma unroll
    for (int s = 0; s < 2; ++s)
#pragma unroll
        for (int r = 0; r < 4; ++r) { minv[s][r] = 3.0e38f; mini[s][r] = 0; }

    const int cl = lane & 15;
    short8 b0h = ebh[lane], b0l = ebl[lane];
    short8 b1h = ebh[64 + lane], b1l = ebl[64 + lane];

    for (int ct = 0; ct < 64; ++ct) {
        short8 ch0 = b0h, cB0 = b0l, ch1 = b1h, cB1 = b1l;
        if (ct < 63) {                         // double-buffer next B-frags
            b0h = ebh[(ct + 1) * 128 + lane];
            b0l = ebl[(ct + 1) * 128 + lane];
            b1h = ebh[(ct + 1) * 128 + 64 + lane];
            b1l = ebl[(ct + 1) * 128 + 64 + lane];
        }
        floatx4 a0 = {0.f, 0.f, 0.f, 0.f};
        floatx4 a1 = {0.f, 0.f, 0.f, 0.f};
        // S = xh*eh + xh*el + xl*eh, fp32 accumulate
        a0 = __builtin_amdgcn_mfma_f32_16x16x32_bf16(ah[0][0], ch0, a0, 0, 0, 0);
        a0 = __builtin_amdgcn_mfma_f32_16x16x32_bf16(ah[0][1], ch1, a0, 0, 0, 0);
        a0 = __builtin_amdgcn_mfma_f32_16x16x32_bf16(ah[0][0], cB0, a0, 0, 0, 0);
        a0 = __builtin_amdgcn_mfma_f32_16x16x32_bf16(ah[0][1], cB1, a0, 0, 0, 0);
        a0 = __builtin_amdgcn_mfma_f32_16x16x32_bf16(al[0][0], ch0, a0, 0, 0, 0);
        a0 = __builtin_amdgcn_mfma_f32_16x16x32_bf16(al[0][1], ch1, a0, 0, 0, 0);
        a1 = __builtin_amdgcn_mfma_f32_16x16x32_bf16(ah[1][0], ch0, a1, 0, 0, 0);
        a1 = __builtin_amdgcn_mfma_f32_16x16x32_bf16(ah[1][1], ch1, a1, 0, 0, 0);
        a1 = __builtin_amdgcn_mfma_f32_16x16x32_bf16(ah[1][0], cB0, a1, 0, 0, 0);
        a1 = __builtin_amdgcn_mfma_f32_16x16x32_bf16(ah[1][1], cB1, a1, 0, 0, 0);
        a1 = __builtin_amdgcn_mfma_f32_16x16x32_bf16(al[1][0], ch0, a1, 0, 0, 0);
        a1 = __builtin_amdgcn_mfma_f32_16x16x32_bf16(al[1][1], ch1, a1, 0, 0, 0);

        const float sel = se[ct * 16 + cl];
        const int  code = ct * 16 + cl;
#pragma unroll
        for (int r = 0; r < 4; ++r) {
            float d0 = fmaf(-2.f, a0[r], sel);
            if (d0 < minv[0][r]) { minv[0][r] = d0; mini[0][r] = code; }
            float d1 = fmaf(-2.f, a1[r], sel);
            if (d1 < minv[1][r]) { minv[1][r] = d1; mini[1][r] = code; }
        }
    }

    // ---- Phase C: reduce (val,idx) across 16 lanes; write idx/ks/hist/loss
    float lossp = 0.f;
#pragma unroll
    for (int s = 0; s < 2; ++s)
#pragma unroll
        for (int r = 0; r < 4; ++r) {
            float v = minv[s][r]; int i = mini[s][r];
#pragma unroll
            for (int m = 1; m <= 8; m <<= 1) {
                float ov = __shfl_xor(v, m, 64);
                int   oi = __shfl_xor(i, m, 64);
                if (ov < v || (ov == v && oi < i)) { v = ov; i = oi; }
            }
            if ((lane & 15) == 0) {
                int row_loc = wid * 32 + s * 16 + (lane >> 4) * 4 + r;
                idxout[rblk + row_loc] = i;
                ks[row_loc] = i;
                atomicAdd(&hist[i], 1);
                lossp += v;                     // d'_min for this row
            }
        }
#pragma unroll
    for (int m = 1; m <= 32; m <<= 1) lossp += __shfl_xor(lossp, m, 64);
    if (lane == 0) atomicAdd(lossacc, lossp);
    __syncthreads();

    // ---- Phase D: enc rows for this wave's 32 rows, lane-contiguous NT stores
#pragma unroll 2
    for (int rr = 0; rr < 32; ++rr) {
        const int row_loc = wid * 32 + rr;
        const int k = ks[row_loc];
        floatx2* p = enc2 + ((size_t)(rblk + row_loc) << 9) + lane;
        const int tf2 = k >> 1, tc = k & 1;
#pragma unroll
        for (int i = 0; i < 8; ++i) {           // f2 index lane + 64*i
            floatx2 zv = {0.f, 0.f};
            if (tf2 == lane + (i << 6)) zv[tc] = 1.0f;
            __builtin_nontemporal_store(zv, &p[(size_t)i << 6]);
        }
    }
}

// ---- quantized NCHW gather, LDS-tiled for coalesced writes (proven R5) ----
__global__ __launch_bounds__(256) void vq_qout_kernel(
    const float4* __restrict__ emb4, const int* __restrict__ idx,
    float* __restrict__ outq)
{
    __shared__ float q[64 * 65];
    __shared__ int ks[64];
    const int tid = threadIdx.x;
    const int n   = blockIdx.x >> 4;
    const int hw0 = (blockIdx.x & 15) << 6;
    if (tid < 64) ks[tid] = idx[(n << 10) + hw0 + tid];
    __syncthreads();
#pragma unroll
    for (int i = 0; i < 4; ++i) {
        int flat = tid + (i << 8);        // 0..1023 = 64 rows x 16 float4
        int hw = flat >> 4;
        int f4 = flat & 15;
        float4 v = emb4[(ks[hw] << 4) + f4];   // 256 B row reads, L2-hot
        float* dst = &q[hw * 65 + (f4 << 2)];
        dst[0] = v.x; dst[1] = v.y; dst[2] = v.z; dst[3] = v.w;
    }
    __syncthreads();
    const int lane_hw = tid & 63;
    const int cw = tid >> 6;              // wave id 0..3 -> c block
    float* ob = outq + ((size_t)n << 16) + hw0 + lane_hw;
#pragma unroll
    for (int j = 0; j < 16; ++j) {
        int c = cw * 16 + j;
        __builtin_nontemporal_store(q[lane_hw * 65 + c], &ob[(size_t)c << 10]);
    }
}

__global__ __launch_bounds__(256) void vq_final_kernel(
    const int* __restrict__ hist, const float* __restrict__ lossacc,
    const float* __restrict__ sumx2, float* __restrict__ out)
{
    const int tid = threadIdx.x;
    float s = 0.f;
    for (int k = tid; k < KCB; k += 256) {
        float p = (float)hist[k] * (1.f / 65536.f);
        s += p * logf(p + 1e-10f);
    }
    __shared__ float red[256];
    red[tid] = s;
    __syncthreads();
    for (int st = 128; st > 0; st >>= 1) {
        if (tid < st) red[tid] += red[tid + st];
        __syncthreads();
    }
    if (tid == 0) {
        // mean||x-q||^2 = (sum x^2 + sum d'_min) / numel
        out[0] = 0.25f * (sumx2[0] + lossacc[0]) * (1.f / 4194304.f);
        out[4194305] = expf(-red[0]);
    }
}

extern "C" void kernel_launch(void* const* d_in, const int* in_sizes, int n_in,
                              void* d_out, int out_size, void* d_ws, size_t ws_size,
                              hipStream_t stream) {
    const float* inp = (const float*)d_in[0];
    const float* emb = (const float*)d_in[1];
    float* out = (float*)d_out;

    float* wsf     = (float*)d_ws;
    float* se      = wsf;                     // 1024 f
    int*   hist    = (int*)(wsf + 1024);      // 1024 i
    float* lossacc = wsf + 2048;              // sum d'_min
    float* sumx2   = wsf + 2049;              // sum x^2
    int*   idx     = (int*)(wsf + 2304);      // 65536 i

    float* outq = out + 1;
    float* enc  = out + 4194306;              // 67,108,864 f (256 MB)

    // B-frags parked in the QUANTIZED region of d_out (dead until vq_qout,
    // which runs after mega). Each array is 32768 floats = 128 KB — R6's bug
    // was spacing them 16384 floats apart. out+4 is 16 B aligned.
    short8* ebh = (short8*)(out + 4);             // 128 KB
    short8* ebl = (short8*)(out + 4 + 32768);     // 128 KB

    vq_init_kernel <<<4,    256, 0, stream>>>(emb, se, hist, lossacc, sumx2, ebh, ebl);
    vq_mega_kernel <<<512,  256, 0, stream>>>(inp, ebh, ebl, se, idx, hist,
                                              lossacc, sumx2, (floatx2*)enc);
    vq_qout_kernel <<<1024, 256, 0, stream>>>((const float4*)emb, idx, outq);
    vq_final_kernel<<<1,    256, 0, stream>>>(hist, lossacc, sumx2, out);
}